// Round 6
// baseline (268.187 us; speedup 1.0000x reference)
//
#include <hip/hip_runtime.h>
#include <stdint.h>
#include <stddef.h>

// Problem constants
#define BB 8
#define CC 16
#define DD 192
#define OCC 4
#define OHH 50
#define OWW 200

#define LDP 200   // padded LDS row stride in bf16 elements (192 + 8)
#define CH  24    // 8-element chunks per 192 row

typedef __attribute__((ext_vector_type(8))) short s8v;   // 8 bf16 = 16B (MFMA A/B frag)
typedef __attribute__((ext_vector_type(4))) short s4v;   // 4 bf16 = 8B
typedef __attribute__((ext_vector_type(4))) float f4v;   // 4 fp32
typedef __attribute__((ext_vector_type(4))) float f32x4; // MFMA C/D frag

__device__ __forceinline__ short rne_bf16(float f) {
  uint32_t u = __float_as_uint(f);
  u += 0x7fffu + ((u >> 16) & 1u);
  return (short)(u >> 16);
}
__device__ __forceinline__ float bf2f(short s) {
  return __uint_as_float(((uint32_t)(uint16_t)s) << 16);
}

// ---------------- fused prep kernel ----------------
// z-segmented grid: [0, NTX)      transpose_x   (x fp32 -> XTb bf16 transposed)
//                   [NTX, +NPT)   transpose_pt  (PT fp32 -> PTTb bf16 transposed)
//                   [.., +NCV)    cvt R fp32 -> bf16
#define NTX (BB * CC * 36)    // 4608 blocks: 6x6 32-tiles per outer
#define NPT (OCC * CC * 42)   // 2688 blocks: 6x7 32-tiles per outer
#define NCV 9216              // (16*16*192*192/4)/256

__global__ __launch_bounds__(256) void prep(const float* __restrict__ x,
                                            const float* __restrict__ R,
                                            const float* __restrict__ PT,
                                            short* __restrict__ XTb,
                                            short* __restrict__ PTTb,
                                            short* __restrict__ Rb) {
  __shared__ float tile[32][33];
  const int z = blockIdx.x;
  const int tid = threadIdx.x;
  const int tx = tid & 31, ty = tid >> 5;
  if (z < NTX) {
    int outer = z / 36, rem = z % 36;
    int p0 = (rem / 6) * 32, q0 = (rem % 6) * 32;
    const float* src = x + (size_t)outer * DD * DD;
    for (int r = ty; r < 32; r += 8)
      tile[r][tx] = src[(size_t)(p0 + r) * DD + q0 + tx];
    __syncthreads();
    short* dst = XTb + (size_t)outer * DD * DD;
    for (int r = ty; r < 32; r += 8)
      dst[(size_t)(q0 + r) * DD + p0 + tx] = rne_bf16(tile[tx][r]);
  } else if (z < NTX + NPT) {
    int z2 = z - NTX;
    int outer = z2 / 42, rem = z2 % 42;
    int q0 = (rem / 7) * 32, n0 = (rem % 7) * 32;
    const float* src = PT + (size_t)outer * DD * OWW;
    for (int r = ty; r < 32; r += 8)
      tile[r][tx] = (n0 + tx < OWW) ? src[(size_t)(q0 + r) * OWW + n0 + tx] : 0.f;
    __syncthreads();
    short* dst = PTTb + (size_t)outer * OWW * DD;
    for (int r = ty; r < 32; r += 8)
      if (n0 + r < OWW) dst[(size_t)(n0 + r) * DD + q0 + tx] = rne_bf16(tile[tx][r]);
  } else {
    int idx = (z - NTX - NPT) * 256 + tid;   // exact: NCV*256 == nR/4
    f4v v = *(const f4v*)(R + (size_t)idx * 4);
    s4v o;
    #pragma unroll
    for (int r = 0; r < 4; ++r) o[r] = rne_bf16(v[r]);
    *(s4v*)(Rb + (size_t)idx * 4) = o;
  }
}

// ---------------- stage A ----------------
// y[b,i] = sum_j R[i,j] @ x[b,j] @ R[i,j]^T, split over jg halves.
// mm1: T^T[q][m] = sum_p XT[q][p] R[m][p]   (A = XT rows in lds2, B = R rows in ldsR)
// mm2: y[m][n]   = sum_q T[m][q] R[n][q]    (A = T rows in lds2, B = R rows in ldsR)
// 1024 threads = 16 waves; wave grid 4x4, 3x3 16-tiles per wave.
// Register prefetch pipeline (proven correct in R4 at 512thr; spilled there, fits here):
// j+1's R/X tiles -> 10 s8v regs issued after mm1, in flight across pack-T + raw
// s_barrier (lgkmcnt-only, no vmcnt drain) + mm2; written to LDS at top of j+1.
// VGPR budget: R5 measured 56 base + 40 prefetch ~= 110 < 128 cap of launch_bounds(1024).
__global__ __launch_bounds__(1024) void stageA(const short* __restrict__ Rb,
                                               const short* __restrict__ XTb,
                                               short* __restrict__ ypart) {
  __shared__ __align__(16) short ldsR[DD * LDP];
  __shared__ __align__(16) short lds2[DD * LDP];
  const int tid = threadIdx.x;
  const int bx = blockIdx.x;            // no XCD swizzle: tripled FETCH, zero gain (R5)
  const int b = bx >> 5, i = (bx >> 1) & 15, jg = bx & 1;
  const int lane15 = tid & 15, quad = (tid & 63) >> 4;
  const int wid = tid >> 6;   // 0..15
  const int wm = wid & 3;     // 4 groups x 3 tiles (B-operand dim)
  const int wq = wid >> 2;    // 4 groups x 3 tiles (A-operand dim)
  const bool has5 = (tid < 512);   // 4608 chunks / 1024 threads = 4.5

  // precomputed LDS offsets for the staging pattern (row/col fixed per thread)
  int loff[5];
  #pragma unroll
  for (int k = 0; k < 5; ++k) {
    int c = tid + k * 1024;
    loff[k] = (c / CH) * LDP + (c % CH) * 8;
  }

  f32x4 acc_y[3][3];
  #pragma unroll
  for (int a = 0; a < 3; ++a)
    #pragma unroll
    for (int c = 0; c < 3; ++c) acc_y[a][c] = (f32x4){0.f, 0.f, 0.f, 0.f};

  const short* srcR0 = Rb + (size_t)(i * CC + jg * 8) * (DD * DD);
  const short* srcX0 = XTb + (size_t)(b * CC + jg * 8) * (DD * DD);

  // prologue: prefetch j = jg*8 tiles into registers
  s8v pfR[5], pfX[5];
  #pragma unroll
  for (int k = 0; k < 4; ++k) {
    size_t c8 = (size_t)(tid + k * 1024) * 8;
    pfR[k] = *(const s8v*)(srcR0 + c8);
    pfX[k] = *(const s8v*)(srcX0 + c8);
  }
  if (has5) {
    size_t c8 = (size_t)(tid + 4096) * 8;
    pfR[4] = *(const s8v*)(srcR0 + c8);
    pfX[4] = *(const s8v*)(srcX0 + c8);
  }

  for (int jj = 0; jj < 8; ++jj) {
    // raw barrier: prev mm2's LDS ops drained per-wave (lgkmcnt), prefetch global
    // loads stay in flight (no vmcnt drain)
    __builtin_amdgcn_sched_barrier(0);
    asm volatile("s_waitcnt lgkmcnt(0)" ::: "memory");
    __builtin_amdgcn_s_barrier();
    __builtin_amdgcn_sched_barrier(0);

    // stage current j from prefetch registers (compiler waits vmcnt per-use)
    #pragma unroll
    for (int k = 0; k < 4; ++k) {
      *(s8v*)(&ldsR[loff[k]]) = pfR[k];
      *(s8v*)(&lds2[loff[k]]) = pfX[k];
    }
    if (has5) {
      *(s8v*)(&ldsR[loff[4]]) = pfR[4];
      *(s8v*)(&lds2[loff[4]]) = pfX[4];
    }
    __syncthreads();   // no prefetch loads in flight here: full drain is fine

    // mm1: T^T  (A = XT rows -> wq covers 3 q-tiles; B = R rows -> wm covers 3 m-tiles)
    f32x4 acc_t[3][3];
    #pragma unroll
    for (int a = 0; a < 3; ++a)
      #pragma unroll
      for (int c = 0; c < 3; ++c) acc_t[a][c] = (f32x4){0.f, 0.f, 0.f, 0.f};

    #pragma unroll
    for (int kc = 0; kc < 6; ++kc) {
      s8v af[3], bf[3];
      #pragma unroll
      for (int a = 0; a < 3; ++a)
        af[a] = *(const s8v*)(&lds2[((wq * 3 + a) * 16 + lane15) * LDP + kc * 32 + quad * 8]);
      #pragma unroll
      for (int c = 0; c < 3; ++c)
        bf[c] = *(const s8v*)(&ldsR[((wm * 3 + c) * 16 + lane15) * LDP + kc * 32 + quad * 8]);
      #pragma unroll
      for (int a = 0; a < 3; ++a)
        #pragma unroll
        for (int c = 0; c < 3; ++c)
          acc_t[a][c] = __builtin_amdgcn_mfma_f32_16x16x32_bf16(af[a], bf[c], acc_t[a][c], 0, 0, 0);
    }
    __syncthreads();   // X fully consumed; no prefetch loads in flight

    // issue next-j prefetch early (in flight across pack + raw barrier + mm2)
    if (jj < 7) {
      const short* srcRn = srcR0 + (size_t)(jj + 1) * (DD * DD);
      const short* srcXn = srcX0 + (size_t)(jj + 1) * (DD * DD);
      #pragma unroll
      for (int k = 0; k < 4; ++k) {
        size_t c8 = (size_t)(tid + k * 1024) * 8;
        pfR[k] = *(const s8v*)(srcRn + c8);
        pfX[k] = *(const s8v*)(srcXn + c8);
      }
      if (has5) {
        size_t c8 = (size_t)(tid + 4096) * 8;
        pfR[4] = *(const s8v*)(srcRn + c8);
        pfX[4] = *(const s8v*)(srcXn + c8);
      }
    }

    // pack T[m][q] (bf16) into lds2
    #pragma unroll
    for (int a = 0; a < 3; ++a) {
      #pragma unroll
      for (int c = 0; c < 3; ++c) {
        s4v pk;
        #pragma unroll
        for (int r = 0; r < 4; ++r) pk[r] = rne_bf16(acc_t[a][c][r]);
        int m = (wm * 3 + c) * 16 + lane15;
        int q0 = (wq * 3 + a) * 16 + quad * 4;
        *(s4v*)(&lds2[m * LDP + q0]) = pk;
      }
    }

    // raw barrier: pack's LDS writes drained per-wave; prefetch loads stay in flight
    __builtin_amdgcn_sched_barrier(0);
    asm volatile("s_waitcnt lgkmcnt(0)" ::: "memory");
    __builtin_amdgcn_s_barrier();
    __builtin_amdgcn_sched_barrier(0);

    // mm2: y[m][n] += T rows x R rows  (A = T -> wq covers 3 m-tiles; B = R -> wm covers 3 n-tiles)
    #pragma unroll
    for (int kc = 0; kc < 6; ++kc) {
      s8v af[3], bf[3];
      #pragma unroll
      for (int a = 0; a < 3; ++a)
        af[a] = *(const s8v*)(&lds2[((wq * 3 + a) * 16 + lane15) * LDP + kc * 32 + quad * 8]);
      #pragma unroll
      for (int c = 0; c < 3; ++c)
        bf[c] = *(const s8v*)(&ldsR[((wm * 3 + c) * 16 + lane15) * LDP + kc * 32 + quad * 8]);
      #pragma unroll
      for (int a = 0; a < 3; ++a)
        #pragma unroll
        for (int c = 0; c < 3; ++c)
          acc_y[a][c] = __builtin_amdgcn_mfma_f32_16x16x32_bf16(af[a], bf[c], acc_y[a][c], 0, 0, 0);
    }
  }

  // pack y^T [n][m] into lds2, then coalesced store
  __syncthreads();
  #pragma unroll
  for (int a = 0; a < 3; ++a) {
    #pragma unroll
    for (int c = 0; c < 3; ++c) {
      s4v pk;
      #pragma unroll
      for (int r = 0; r < 4; ++r) pk[r] = rne_bf16(acc_y[a][c][r]);
      int n = (wm * 3 + c) * 16 + lane15;       // B-row = n (col of y)
      int m0 = (wq * 3 + a) * 16 + quad * 4;    // A-row = m, 4 consecutive
      *(s4v*)(&lds2[n * LDP + m0]) = pk;
    }
  }
  __syncthreads();
  {
    short* dst = ypart + (size_t)(jg * (BB * CC) + b * CC + i) * (DD * DD);
    for (int c = tid; c < DD * CH; c += 1024) {
      int row = c / CH, col = c % CH;
      *(s8v*)(dst + (size_t)c * 8) = *(const s8v*)(&lds2[row * LDP + col * 8]);
    }
  }
}

// ---------------- fused stage B ----------------
// out[b,oc] = sum_j P[oc,j] @ y[b,j] @ PT[oc,j]
// y = ypart0 + ypart1 summed during staging (sum_y fused); P staged from fp32 (cvt fused).
#define PROWS 64
#define PTROWS 128
__global__ __launch_bounds__(512, 2) void fusedB(const short* __restrict__ ypart,
                                                 const float* __restrict__ Pf,
                                                 const short* __restrict__ PTTb,
                                                 float* __restrict__ partials) {
  __shared__ __align__(16) short ldsYT[DD * LDP];     // 76.8 KB; rows 0..63 reused for U
  __shared__ __align__(16) short ldsP[PROWS * LDP];   // 25.6 KB
  __shared__ __align__(16) short ldsPT[PTROWS * LDP]; // 51.2 KB
  const int tid = threadIdx.x;
  const int bx0 = blockIdx.x;
  const int bx = (bx0 & 7) * 32 + (bx0 >> 3);   // XCD-chunked swizzle
  const int jg = bx & 3, nh = (bx >> 2) & 1, oc = (bx >> 3) & 3, b = bx >> 5;
  const int lane15 = tid & 15, quad = (tid & 63) >> 4;
  const int wid = tid >> 6;
  // mm_b1 wave grid: 4 (q) x 2 (m)
  const int wq1 = wid >> 1, wm1 = wid & 1;
  // mm_b2 wave grid: 2 (m) x 4 (n)
  const int wm2 = wid & 1, wn2 = wid >> 1;

  f32x4 acc_o[2][2];
  #pragma unroll
  for (int a = 0; a < 2; ++a)
    #pragma unroll
    for (int e = 0; e < 2; ++e) acc_o[a][e] = (f32x4){0.f, 0.f, 0.f, 0.f};

  const s8v z = {0, 0, 0, 0, 0, 0, 0, 0};
  for (int jj = 0; jj < 4; ++jj) {
    const int j = jg * 4 + jj;
    __syncthreads();  // prev iter done reading U/ldsP/ldsPT
    {
      const short* sy0 = ypart + (size_t)(b * CC + j) * (DD * DD);
      const short* sy1 = sy0 + (size_t)(BB * CC) * (DD * DD);
      for (int c = tid; c < DD * CH; c += 512) {
        int row = c / CH, col = c % CH;
        s8v v0 = *(const s8v*)(sy0 + (size_t)c * 8);
        s8v v1 = *(const s8v*)(sy1 + (size_t)c * 8);
        s8v o;
        #pragma unroll
        for (int r = 0; r < 8; ++r) o[r] = rne_bf16(bf2f(v0[r]) + bf2f(v1[r]));
        *(s8v*)(&ldsYT[row * LDP + col * 8]) = o;
      }
      const float* sp = Pf + (size_t)(oc * CC + j) * (OHH * DD);
      for (int c = tid; c < PROWS * CH; c += 512) {
        int row = c / CH, col = c % CH;
        s8v w = z;
        if (c < OHH * CH) {
          f4v v0 = *(const f4v*)(sp + (size_t)c * 8);
          f4v v1 = *(const f4v*)(sp + (size_t)c * 8 + 4);
          #pragma unroll
          for (int r = 0; r < 4; ++r) w[r] = rne_bf16(v0[r]);
          #pragma unroll
          for (int r = 0; r < 4; ++r) w[r + 4] = rne_bf16(v1[r]);
        }
        *(s8v*)(&ldsP[row * LDP + col * 8]) = w;
      }
      const short* st = PTTb + (size_t)(oc * CC + j) * (OWW * DD) + (size_t)nh * 100 * DD;
      for (int c = tid; c < PTROWS * CH; c += 512) {
        int row = c / CH, col = c % CH;
        *(s8v*)(&ldsPT[row * LDP + col * 8]) =
            (c < 100 * CH) ? *(const s8v*)(st + (size_t)c * 8) : z;
      }
    }
    __syncthreads();

    // mm_b1: U^T[q][m]; wq1 -> 3 q-tiles, wm1 -> 2 m-tiles
    f32x4 acc_t[3][2];
    #pragma unroll
    for (int a = 0; a < 3; ++a)
      #pragma unroll
      for (int c = 0; c < 2; ++c) acc_t[a][c] = (f32x4){0.f, 0.f, 0.f, 0.f};
    #pragma unroll
    for (int kc = 0; kc < 6; ++kc) {
      s8v af[3], bf[2];
      #pragma unroll
      for (int a = 0; a < 3; ++a)
        af[a] = *(const s8v*)(&ldsYT[((wq1 * 3 + a) * 16 + lane15) * LDP + kc * 32 + quad * 8]);
      #pragma unroll
      for (int c = 0; c < 2; ++c)
        bf[c] = *(const s8v*)(&ldsP[((wm1 * 2 + c) * 16 + lane15) * LDP + kc * 32 + quad * 8]);
      #pragma unroll
      for (int a = 0; a < 3; ++a)
        #pragma unroll
        for (int c = 0; c < 2; ++c)
          acc_t[a][c] = __builtin_amdgcn_mfma_f32_16x16x32_bf16(af[a], bf[c], acc_t[a][c], 0, 0, 0);
    }
    __syncthreads();  // yT fully consumed

    // pack U[m][q] into ldsYT rows 0..63
    #pragma unroll
    for (int a = 0; a < 3; ++a) {
      #pragma unroll
      for (int c = 0; c < 2; ++c) {
        s4v pk;
        #pragma unroll
        for (int r = 0; r < 4; ++r) pk[r] = rne_bf16(acc_t[a][c][r]);
        int m = (wm1 * 2 + c) * 16 + lane15;
        int q0 = (wq1 * 3 + a) * 16 + quad * 4;
        *(s4v*)(&ldsYT[m * LDP + q0]) = pk;
      }
    }
    __syncthreads();

    // mm_b2: out[m][n] += U rows x PT^T rows; wm2 -> 2 m-tiles, wn2 -> 2 n-tiles
    #pragma unroll
    for (int kc = 0; kc < 6; ++kc) {
      s8v af[2], bf[2];
      #pragma unroll
      for (int a = 0; a < 2; ++a)
        af[a] = *(const s8v*)(&ldsYT[((wm2 * 2 + a) * 16 + lane15) * LDP + kc * 32 + quad * 8]);
      #pragma unroll
      for (int e = 0; e < 2; ++e)
        bf[e] = *(const s8v*)(&ldsPT[((wn2 * 2 + e) * 16 + lane15) * LDP + kc * 32 + quad * 8]);
      #pragma unroll
      for (int a = 0; a < 2; ++a)
        #pragma unroll
        for (int e = 0; e < 2; ++e)
          acc_o[a][e] = __builtin_amdgcn_mfma_f32_16x16x32_bf16(af[a], bf[e], acc_o[a][e], 0, 0, 0);
    }
  }

  // store fp32 partial: partials[jg][b*OCC+oc][m][nh*100 + n]
  float* dst = partials + ((size_t)jg * (BB * OCC) + b * OCC + oc) * (OHH * OWW);
  #pragma unroll
  for (int a = 0; a < 2; ++a) {
    #pragma unroll
    for (int e = 0; e < 2; ++e) {
      int n = (wn2 * 2 + e) * 16 + lane15;
      if (n < 100) {
        #pragma unroll
        for (int r = 0; r < 4; ++r) {
          int m = (wm2 * 2 + a) * 16 + quad * 4 + r;
          if (m < OHH)
            dst[(size_t)m * OWW + nh * 100 + n] = acc_o[a][e][r];
        }
      }
    }
  }
}

// ---------------- reduce: out = sum of 4 jg partials ----------------
__global__ void reduce_out(const float* __restrict__ partials, float* __restrict__ out, int n4) {
  int idx = blockIdx.x * 256 + threadIdx.x;
  if (idx >= n4) return;
  const size_t stride = (size_t)(BB * OCC) * OHH * OWW;
  f4v s = *(const f4v*)(partials + (size_t)idx * 4);
  #pragma unroll
  for (int g = 1; g < 4; ++g) {
    f4v v = *(const f4v*)(partials + g * stride + (size_t)idx * 4);
    #pragma unroll
    for (int r = 0; r < 4; ++r) s[r] += v[r];
  }
  *(f4v*)(out + (size_t)idx * 4) = s;
}

// ---------------- launcher ----------------

extern "C" void kernel_launch(void* const* d_in, const int* in_sizes, int n_in,
                              void* d_out, int out_size, void* d_ws, size_t ws_size,
                              hipStream_t stream) {
  const float* x  = (const float*)d_in[0];
  const float* R  = (const float*)d_in[1];
  const float* P  = (const float*)d_in[2];
  const float* PT = (const float*)d_in[3];
  float* out = (float*)d_out;

  short* W = (short*)d_ws;
  const size_t nR   = (size_t)CC * CC * DD * DD;     // 9,437,184
  const size_t nX   = (size_t)BB * CC * DD * DD;     // 4,718,592
  const size_t nPT  = (size_t)OCC * CC * OWW * DD;   // 2,457,600
  short* Rb    = W;
  short* XTb   = Rb + nR;
  short* PTTb  = XTb + nX;
  short* ypart = PTTb + nPT;                         // 2 halves
  float* parts = (float*)(ypart + 2 * nX);           // 4 * 32 * 50 * 200 fp32 = 5.12 MB

  prep<<<NTX + NPT + NCV, 256, 0, stream>>>(x, R, PT, XTb, PTTb, Rb);

  stageA<<<BB * CC * 2, 1024, 0, stream>>>(Rb, XTb, ypart);
  fusedB<<<BB * OCC * 2 * 4, 512, 0, stream>>>(ypart, P, PTTb, parts);

  const int n4 = BB * OCC * OHH * OWW / 4;  // 80,000
  reduce_out<<<(n4 + 255) / 256, 256, 0, stream>>>(parts, out, n4);
}

// Round 7
// 265.845 us; speedup vs baseline: 1.0088x; 1.0088x over previous
//
#include <hip/hip_runtime.h>
#include <stdint.h>
#include <stddef.h>

// Problem constants
#define BB 8
#define CC 16
#define DD 192
#define OCC 4
#define OHH 50
#define OWW 200

#define LDP 200     // padded LDS row stride (fusedB only)
#define CH  24      // 8-element chunks per 192 row
#define DSTRIDE 192 // dense LDS row stride in shorts (stageA; gload_lds-compatible)

typedef __attribute__((ext_vector_type(8))) short s8v;   // 8 bf16 = 16B (MFMA A/B frag)
typedef __attribute__((ext_vector_type(4))) short s4v;   // 4 bf16 = 8B
typedef __attribute__((ext_vector_type(4))) float f4v;   // 4 fp32
typedef __attribute__((ext_vector_type(4))) float f32x4; // MFMA C/D frag

__device__ __forceinline__ short rne_bf16(float f) {
  uint32_t u = __float_as_uint(f);
  u += 0x7fffu + ((u >> 16) & 1u);
  return (short)(u >> 16);
}
__device__ __forceinline__ float bf2f(short s) {
  return __uint_as_float(((uint32_t)(uint16_t)s) << 16);
}

// global -> LDS direct DMA, 16B per lane. LDS dest must be wave-uniform base;
// HW writes base + lane*16. Global src is per-lane.
__device__ __forceinline__ void gload16(const short* g, short* l) {
  __builtin_amdgcn_global_load_lds(
      (const __attribute__((address_space(1))) void*)g,
      (__attribute__((address_space(3))) void*)l, 16, 0, 0);
}

// ---------------- fused prep kernel ----------------
// z-segmented grid: [0, NTX)      transpose_x   (x fp32 -> XTb bf16 transposed)
//                   [NTX, +NPT)   transpose_pt  (PT fp32 -> PTTb bf16 transposed)
//                   [.., +NCV)    cvt R fp32 -> bf16
#define NTX (BB * CC * 36)    // 4608 blocks: 6x6 32-tiles per outer
#define NPT (OCC * CC * 42)   // 2688 blocks: 6x7 32-tiles per outer
#define NCV 9216              // (16*16*192*192/4)/256

__global__ __launch_bounds__(256) void prep(const float* __restrict__ x,
                                            const float* __restrict__ R,
                                            const float* __restrict__ PT,
                                            short* __restrict__ XTb,
                                            short* __restrict__ PTTb,
                                            short* __restrict__ Rb) {
  __shared__ float tile[32][33];
  const int z = blockIdx.x;
  const int tid = threadIdx.x;
  const int tx = tid & 31, ty = tid >> 5;
  if (z < NTX) {
    int outer = z / 36, rem = z % 36;
    int p0 = (rem / 6) * 32, q0 = (rem % 6) * 32;
    const float* src = x + (size_t)outer * DD * DD;
    for (int r = ty; r < 32; r += 8)
      tile[r][tx] = src[(size_t)(p0 + r) * DD + q0 + tx];
    __syncthreads();
    short* dst = XTb + (size_t)outer * DD * DD;
    for (int r = ty; r < 32; r += 8)
      dst[(size_t)(q0 + r) * DD + p0 + tx] = rne_bf16(tile[tx][r]);
  } else if (z < NTX + NPT) {
    int z2 = z - NTX;
    int outer = z2 / 42, rem = z2 % 42;
    int q0 = (rem / 7) * 32, n0 = (rem % 7) * 32;
    const float* src = PT + (size_t)outer * DD * OWW;
    for (int r = ty; r < 32; r += 8)
      tile[r][tx] = (n0 + tx < OWW) ? src[(size_t)(q0 + r) * OWW + n0 + tx] : 0.f;
    __syncthreads();
    short* dst = PTTb + (size_t)outer * OWW * DD;
    for (int r = ty; r < 32; r += 8)
      if (n0 + r < OWW) dst[(size_t)(n0 + r) * DD + q0 + tx] = rne_bf16(tile[tx][r]);
  } else {
    int idx = (z - NTX - NPT) * 256 + tid;   // exact: NCV*256 == nR/4
    f4v v = *(const f4v*)(R + (size_t)idx * 4);
    s4v o;
    #pragma unroll
    for (int r = 0; r < 4; ++r) o[r] = rne_bf16(v[r]);
    *(s4v*)(Rb + (size_t)idx * 4) = o;
  }
}

// ---------------- stage A ----------------
// y[b,i] = sum_j R[i,j] @ x[b,j] @ R[i,j]^T, split over jg halves.
// mm1: T^T[q][m] = sum_p XT[q][p] R[m][p]   (A = XT rows in lds2, B = R rows in ldsR)
// mm2: y[m][n]   = sum_q T[m][q] R[n][q]    (A = T rows in lds2, B = R rows in ldsR)
// LDS: dense 384-B rows (no padding) + XOR-chunk swizzle:
//   physical 16B-chunk = logical_chunk ^ (row & 7).
//   Bank math: row stride 96 dw == 0 mod 32; group(l) = (chunk^l) mod 8 is a
//   permutation over lanes 0..7 -> 2-way (l, l+8) pairing = b128 floor, same as
//   the old LDP=200 padding, but the layout is LINEAR so global_load_lds works:
//   LDS dest linear, XOR applied to the per-lane GLOBAL source address (m173).
// Staging = global_load_lds only (no VGPR round-trip, no spill risk).
__global__ __launch_bounds__(1024) void stageA(const short* __restrict__ Rb,
                                               const short* __restrict__ XTb,
                                               short* __restrict__ ypart) {
  __shared__ __align__(16) short ldsR[DD * DSTRIDE];   // 73728 B
  __shared__ __align__(16) short lds2[DD * DSTRIDE];   // 73728 B
  const int tid = threadIdx.x;
  const int bx = blockIdx.x;   // no XCD swizzle (R5: tripled FETCH, zero gain)
  const int b = bx >> 5, i = (bx >> 1) & 15, jg = bx & 1;
  const int lane15 = tid & 15, quad = (tid & 63) >> 4;
  const int lane = tid & 63;
  const int wid = tid >> 6;   // 0..15
  const int wm = wid & 3;     // 4 groups x 3 tiles (B-operand dim)
  const int wq = wid >> 2;    // 4 groups x 3 tiles (A-operand dim)
  const int key = lane15 & 7; // XOR key: == row&7 for every row this lane touches

  // gload segments: 73728 B / 1024 B = 72 segs; wave w takes segs w, w+16, ...
  // precompute per-lane pre-swizzled source offsets (shorts)
  int gsrc[5];
  #pragma unroll
  for (int t = 0; t < 5; ++t) {
    int off = (wid + t * 16) * 1024 + lane * 16;  // byte offset in dense buffer
    int row = off / 384;
    int ch = (off % 384) >> 4;
    gsrc[t] = row * DSTRIDE + ((ch ^ (row & 7)) << 3);
  }

  f32x4 acc_y[3][3];
  #pragma unroll
  for (int a = 0; a < 3; ++a)
    #pragma unroll
    for (int c = 0; c < 3; ++c) acc_y[a][c] = (f32x4){0.f, 0.f, 0.f, 0.f};

  for (int jj = 0; jj < 8; ++jj) {
    const int j = jg * 8 + jj;
    const short* srcR = Rb + (size_t)(i * CC + j) * (DD * DD);
    const short* srcX = XTb + (size_t)(b * CC + j) * (DD * DD);
    __syncthreads();  // previous iter done reading ldsR/lds2
    #pragma unroll
    for (int t = 0; t < 5; ++t) {
      int seg = wid + t * 16;
      if (seg < 72) {                       // wave-uniform condition
        gload16(srcR + gsrc[t], &ldsR[seg * 512]);
        gload16(srcX + gsrc[t], &lds2[seg * 512]);
      }
    }
    __syncthreads();  // drains vmcnt: gload_lds data visible

    // mm1: T^T  (A = XT rows -> wq covers 3 q-tiles; B = R rows -> wm covers 3 m-tiles)
    f32x4 acc_t[3][3];
    #pragma unroll
    for (int a = 0; a < 3; ++a)
      #pragma unroll
      for (int c = 0; c < 3; ++c) acc_t[a][c] = (f32x4){0.f, 0.f, 0.f, 0.f};

    #pragma unroll
    for (int kc = 0; kc < 6; ++kc) {
      s8v af[3], bf[3];
      const int cph = (((kc * 4 + quad) ^ key) << 3);
      #pragma unroll
      for (int a = 0; a < 3; ++a)
        af[a] = *(const s8v*)(&lds2[((wq * 3 + a) * 16 + lane15) * DSTRIDE + cph]);
      #pragma unroll
      for (int c = 0; c < 3; ++c)
        bf[c] = *(const s8v*)(&ldsR[((wm * 3 + c) * 16 + lane15) * DSTRIDE + cph]);
      #pragma unroll
      for (int a = 0; a < 3; ++a)
        #pragma unroll
        for (int c = 0; c < 3; ++c)
          acc_t[a][c] = __builtin_amdgcn_mfma_f32_16x16x32_bf16(af[a], bf[c], acc_t[a][c], 0, 0, 0);
    }
    __syncthreads();   // X fully consumed

    // pack T[m][q] (bf16) into lds2 (swizzled write, keyed by m&7 == lane15&7)
    #pragma unroll
    for (int a = 0; a < 3; ++a) {
      #pragma unroll
      for (int c = 0; c < 3; ++c) {
        s4v pk;
        #pragma unroll
        for (int r = 0; r < 4; ++r) pk[r] = rne_bf16(acc_t[a][c][r]);
        int m = (wm * 3 + c) * 16 + lane15;
        int q0 = (wq * 3 + a) * 16 + quad * 4;
        *(s4v*)(&lds2[m * DSTRIDE + (((q0 >> 3) ^ key) << 3) + (q0 & 7)]) = pk;
      }
    }
    __syncthreads();

    // mm2: y[m][n] += T rows x R rows  (A = T -> wq covers 3 m-tiles; B = R -> wm covers 3 n-tiles)
    #pragma unroll
    for (int kc = 0; kc < 6; ++kc) {
      s8v af[3], bf[3];
      const int cph = (((kc * 4 + quad) ^ key) << 3);
      #pragma unroll
      for (int a = 0; a < 3; ++a)
        af[a] = *(const s8v*)(&lds2[((wq * 3 + a) * 16 + lane15) * DSTRIDE + cph]);
      #pragma unroll
      for (int c = 0; c < 3; ++c)
        bf[c] = *(const s8v*)(&ldsR[((wm * 3 + c) * 16 + lane15) * DSTRIDE + cph]);
      #pragma unroll
      for (int a = 0; a < 3; ++a)
        #pragma unroll
        for (int c = 0; c < 3; ++c)
          acc_y[a][c] = __builtin_amdgcn_mfma_f32_16x16x32_bf16(af[a], bf[c], acc_y[a][c], 0, 0, 0);
    }
  }

  // pack y^T [n][m] into lds2 (swizzled, keyed by n&7), then coalesced store
  __syncthreads();
  #pragma unroll
  for (int a = 0; a < 3; ++a) {
    #pragma unroll
    for (int c = 0; c < 3; ++c) {
      s4v pk;
      #pragma unroll
      for (int r = 0; r < 4; ++r) pk[r] = rne_bf16(acc_y[a][c][r]);
      int n = (wm * 3 + c) * 16 + lane15;       // B-row = n (col of y)
      int m0 = (wq * 3 + a) * 16 + quad * 4;    // A-row = m, 4 consecutive
      *(s4v*)(&lds2[n * DSTRIDE + (((m0 >> 3) ^ key) << 3) + (m0 & 7)]) = pk;
    }
  }
  __syncthreads();
  {
    short* dst = ypart + (size_t)(jg * (BB * CC) + b * CC + i) * (DD * DD);
    for (int c = tid; c < DD * CH; c += 1024) {
      int row = c / CH, col = c % CH;
      *(s8v*)(dst + (size_t)c * 8) =
          *(const s8v*)(&lds2[row * DSTRIDE + ((col ^ (row & 7)) << 3)]);
    }
  }
}

// ---------------- fused stage B ----------------
// out[b,oc] = sum_j P[oc,j] @ y[b,j] @ PT[oc,j]
// y = ypart0 + ypart1 summed during staging (sum_y fused); P staged from fp32 (cvt fused).
#define PROWS 64
#define PTROWS 128
__global__ __launch_bounds__(512, 2) void fusedB(const short* __restrict__ ypart,
                                                 const float* __restrict__ Pf,
                                                 const short* __restrict__ PTTb,
                                                 float* __restrict__ partials) {
  __shared__ __align__(16) short ldsYT[DD * LDP];     // 76.8 KB; rows 0..63 reused for U
  __shared__ __align__(16) short ldsP[PROWS * LDP];   // 25.6 KB
  __shared__ __align__(16) short ldsPT[PTROWS * LDP]; // 51.2 KB
  const int tid = threadIdx.x;
  const int bx0 = blockIdx.x;
  const int bx = (bx0 & 7) * 32 + (bx0 >> 3);   // XCD-chunked swizzle
  const int jg = bx & 3, nh = (bx >> 2) & 1, oc = (bx >> 3) & 3, b = bx >> 5;
  const int lane15 = tid & 15, quad = (tid & 63) >> 4;
  const int wid = tid >> 6;
  // mm_b1 wave grid: 4 (q) x 2 (m)
  const int wq1 = wid >> 1, wm1 = wid & 1;
  // mm_b2 wave grid: 2 (m) x 4 (n)
  const int wm2 = wid & 1, wn2 = wid >> 1;

  f32x4 acc_o[2][2];
  #pragma unroll
  for (int a = 0; a < 2; ++a)
    #pragma unroll
    for (int e = 0; e < 2; ++e) acc_o[a][e] = (f32x4){0.f, 0.f, 0.f, 0.f};

  const s8v z = {0, 0, 0, 0, 0, 0, 0, 0};
  for (int jj = 0; jj < 4; ++jj) {
    const int j = jg * 4 + jj;
    __syncthreads();  // prev iter done reading U/ldsP/ldsPT
    {
      const short* sy0 = ypart + (size_t)(b * CC + j) * (DD * DD);
      const short* sy1 = sy0 + (size_t)(BB * CC) * (DD * DD);
      for (int c = tid; c < DD * CH; c += 512) {
        int row = c / CH, col = c % CH;
        s8v v0 = *(const s8v*)(sy0 + (size_t)c * 8);
        s8v v1 = *(const s8v*)(sy1 + (size_t)c * 8);
        s8v o;
        #pragma unroll
        for (int r = 0; r < 8; ++r) o[r] = rne_bf16(bf2f(v0[r]) + bf2f(v1[r]));
        *(s8v*)(&ldsYT[row * LDP + col * 8]) = o;
      }
      const float* sp = Pf + (size_t)(oc * CC + j) * (OHH * DD);
      for (int c = tid; c < PROWS * CH; c += 512) {
        int row = c / CH, col = c % CH;
        s8v w = z;
        if (c < OHH * CH) {
          f4v v0 = *(const f4v*)(sp + (size_t)c * 8);
          f4v v1 = *(const f4v*)(sp + (size_t)c * 8 + 4);
          #pragma unroll
          for (int r = 0; r < 4; ++r) w[r] = rne_bf16(v0[r]);
          #pragma unroll
          for (int r = 0; r < 4; ++r) w[r + 4] = rne_bf16(v1[r]);
        }
        *(s8v*)(&ldsP[row * LDP + col * 8]) = w;
      }
      const short* st = PTTb + (size_t)(oc * CC + j) * (OWW * DD) + (size_t)nh * 100 * DD;
      for (int c = tid; c < PTROWS * CH; c += 512) {
        int row = c / CH, col = c % CH;
        *(s8v*)(&ldsPT[row * LDP + col * 8]) =
            (c < 100 * CH) ? *(const s8v*)(st + (size_t)c * 8) : z;
      }
    }
    __syncthreads();

    // mm_b1: U^T[q][m]; wq1 -> 3 q-tiles, wm1 -> 2 m-tiles
    f32x4 acc_t[3][2];
    #pragma unroll
    for (int a = 0; a < 3; ++a)
      #pragma unroll
      for (int c = 0; c < 2; ++c) acc_t[a][c] = (f32x4){0.f, 0.f, 0.f, 0.f};
    #pragma unroll
    for (int kc = 0; kc < 6; ++kc) {
      s8v af[3], bf[2];
      #pragma unroll
      for (int a = 0; a < 3; ++a)
        af[a] = *(const s8v*)(&ldsYT[((wq1 * 3 + a) * 16 + lane15) * LDP + kc * 32 + quad * 8]);
      #pragma unroll
      for (int c = 0; c < 2; ++c)
        bf[c] = *(const s8v*)(&ldsP[((wm1 * 2 + c) * 16 + lane15) * LDP + kc * 32 + quad * 8]);
      #pragma unroll
      for (int a = 0; a < 3; ++a)
        #pragma unroll
        for (int c = 0; c < 2; ++c)
          acc_t[a][c] = __builtin_amdgcn_mfma_f32_16x16x32_bf16(af[a], bf[c], acc_t[a][c], 0, 0, 0);
    }
    __syncthreads();  // yT fully consumed

    // pack U[m][q] into ldsYT rows 0..63
    #pragma unroll
    for (int a = 0; a < 3; ++a) {
      #pragma unroll
      for (int c = 0; c < 2; ++c) {
        s4v pk;
        #pragma unroll
        for (int r = 0; r < 4; ++r) pk[r] = rne_bf16(acc_t[a][c][r]);
        int m = (wm1 * 2 + c) * 16 + lane15;
        int q0 = (wq1 * 3 + a) * 16 + quad * 4;
        *(s4v*)(&ldsYT[m * LDP + q0]) = pk;
      }
    }
    __syncthreads();

    // mm_b2: out[m][n] += U rows x PT^T rows; wm2 -> 2 m-tiles, wn2 -> 2 n-tiles
    #pragma unroll
    for (int kc = 0; kc < 6; ++kc) {
      s8v af[2], bf[2];
      #pragma unroll
      for (int a = 0; a < 2; ++a)
        af[a] = *(const s8v*)(&ldsYT[((wm2 * 2 + a) * 16 + lane15) * LDP + kc * 32 + quad * 8]);
      #pragma unroll
      for (int e = 0; e < 2; ++e)
        bf[e] = *(const s8v*)(&ldsPT[((wn2 * 2 + e) * 16 + lane15) * LDP + kc * 32 + quad * 8]);
      #pragma unroll
      for (int a = 0; a < 2; ++a)
        #pragma unroll
        for (int e = 0; e < 2; ++e)
          acc_o[a][e] = __builtin_amdgcn_mfma_f32_16x16x32_bf16(af[a], bf[e], acc_o[a][e], 0, 0, 0);
    }
  }

  // store fp32 partial: partials[jg][b*OCC+oc][m][nh*100 + n]
  float* dst = partials + ((size_t)jg * (BB * OCC) + b * OCC + oc) * (OHH * OWW);
  #pragma unroll
  for (int a = 0; a < 2; ++a) {
    #pragma unroll
    for (int e = 0; e < 2; ++e) {
      int n = (wn2 * 2 + e) * 16 + lane15;
      if (n < 100) {
        #pragma unroll
        for (int r = 0; r < 4; ++r) {
          int m = (wm2 * 2 + a) * 16 + quad * 4 + r;
          if (m < OHH)
            dst[(size_t)m * OWW + nh * 100 + n] = acc_o[a][e][r];
        }
      }
    }
  }
}

// ---------------- reduce: out = sum of 4 jg partials ----------------
__global__ void reduce_out(const float* __restrict__ partials, float* __restrict__ out, int n4) {
  int idx = blockIdx.x * 256 + threadIdx.x;
  if (idx >= n4) return;
  const size_t stride = (size_t)(BB * OCC) * OHH * OWW;
  f4v s = *(const f4v*)(partials + (size_t)idx * 4);
  #pragma unroll
  for (int g = 1; g < 4; ++g) {
    f4v v = *(const f4v*)(partials + g * stride + (size_t)idx * 4);
    #pragma unroll
    for (int r = 0; r < 4; ++r) s[r] += v[r];
  }
  *(f4v*)(out + (size_t)idx * 4) = s;
}

// ---------------- launcher ----------------

extern "C" void kernel_launch(void* const* d_in, const int* in_sizes, int n_in,
                              void* d_out, int out_size, void* d_ws, size_t ws_size,
                              hipStream_t stream) {
  const float* x  = (const float*)d_in[0];
  const float* R  = (const float*)d_in[1];
  const float* P  = (const float*)d_in[2];
  const float* PT = (const float*)d_in[3];
  float* out = (float*)d_out;

  short* W = (short*)d_ws;
  const size_t nR   = (size_t)CC * CC * DD * DD;     // 9,437,184
  const size_t nX   = (size_t)BB * CC * DD * DD;     // 4,718,592
  const size_t nPT  = (size_t)OCC * CC * OWW * DD;   // 2,457,600
  short* Rb    = W;
  short* XTb   = Rb + nR;
  short* PTTb  = XTb + nX;
  short* ypart = PTTb + nPT;                         // 2 halves
  float* parts = (float*)(ypart + 2 * nX);           // 4 * 32 * 50 * 200 fp32 = 5.12 MB

  prep<<<NTX + NPT + NCV, 256, 0, stream>>>(x, R, PT, XTb, PTTb, Rb);

  stageA<<<BB * CC * 2, 1024, 0, stream>>>(Rb, XTb, ypart);
  fusedB<<<BB * OCC * 2 * 4, 512, 0, stream>>>(ypart, P, PTTb, parts);

  const int n4 = BB * OCC * OHH * OWW / 4;  // 80,000
  reduce_out<<<(n4 + 255) / 256, 256, 0, stream>>>(parts, out, n4);
}

// Round 8
// 215.658 us; speedup vs baseline: 1.2436x; 1.2327x over previous
//
#include <hip/hip_runtime.h>
#include <stdint.h>
#include <stddef.h>

// Problem constants
#define BB 8
#define CC 16
#define DD 192
#define OCC 4
#define OHH 50
#define OWW 200

#define LDP 200   // padded LDS row stride in bf16 elements (192 + 8)
#define CH  24    // 8-element chunks per 192 row

typedef __attribute__((ext_vector_type(8))) short s8v;   // 8 bf16 = 16B (MFMA A/B frag)
typedef __attribute__((ext_vector_type(4))) short s4v;   // 4 bf16 = 8B
typedef __attribute__((ext_vector_type(4))) float f4v;   // 4 fp32
typedef __attribute__((ext_vector_type(4))) float f32x4; // MFMA C/D frag

__device__ __forceinline__ short rne_bf16(float f) {
  uint32_t u = __float_as_uint(f);
  u += 0x7fffu + ((u >> 16) & 1u);
  return (short)(u >> 16);
}
__device__ __forceinline__ float bf2f(short s) {
  return __uint_as_float(((uint32_t)(uint16_t)s) << 16);
}

// ---------------- fused prep kernel ----------------
// z-segmented grid: [0, NTX)      transpose_x   (x fp32 -> XTb bf16 transposed)
//                   [NTX, +NPT)   transpose_pt  (PT fp32 -> PTTb bf16 transposed)
//                   [.., +NCV)    cvt R fp32 -> bf16
#define NTX (BB * CC * 36)    // 4608 blocks: 6x6 32-tiles per outer
#define NPT (OCC * CC * 42)   // 2688 blocks: 6x7 32-tiles per outer
#define NCV 9216              // (16*16*192*192/4)/256

__global__ __launch_bounds__(256) void prep(const float* __restrict__ x,
                                            const float* __restrict__ R,
                                            const float* __restrict__ PT,
                                            short* __restrict__ XTb,
                                            short* __restrict__ PTTb,
                                            short* __restrict__ Rb) {
  __shared__ float tile[32][33];
  const int z = blockIdx.x;
  const int tid = threadIdx.x;
  const int tx = tid & 31, ty = tid >> 5;
  if (z < NTX) {
    int outer = z / 36, rem = z % 36;
    int p0 = (rem / 6) * 32, q0 = (rem % 6) * 32;
    const float* src = x + (size_t)outer * DD * DD;
    for (int r = ty; r < 32; r += 8)
      tile[r][tx] = src[(size_t)(p0 + r) * DD + q0 + tx];
    __syncthreads();
    short* dst = XTb + (size_t)outer * DD * DD;
    for (int r = ty; r < 32; r += 8)
      dst[(size_t)(q0 + r) * DD + p0 + tx] = rne_bf16(tile[tx][r]);
  } else if (z < NTX + NPT) {
    int z2 = z - NTX;
    int outer = z2 / 42, rem = z2 % 42;
    int q0 = (rem / 7) * 32, n0 = (rem % 7) * 32;
    const float* src = PT + (size_t)outer * DD * OWW;
    for (int r = ty; r < 32; r += 8)
      tile[r][tx] = (n0 + tx < OWW) ? src[(size_t)(q0 + r) * OWW + n0 + tx] : 0.f;
    __syncthreads();
    short* dst = PTTb + (size_t)outer * OWW * DD;
    for (int r = ty; r < 32; r += 8)
      if (n0 + r < OWW) dst[(size_t)(n0 + r) * DD + q0 + tx] = rne_bf16(tile[tx][r]);
  } else {
    int idx = (z - NTX - NPT) * 256 + tid;   // exact: NCV*256 == nR/4
    f4v v = *(const f4v*)(R + (size_t)idx * 4);
    s4v o;
    #pragma unroll
    for (int r = 0; r < 4; ++r) o[r] = rne_bf16(v[r]);
    *(s4v*)(Rb + (size_t)idx * 4) = o;
  }
}

// ---------------- stage A ----------------
// EXACT R5 kernel (proven 74.8 us): 1024 threads = 16 waves, 4x4 wave grid,
// 3x3 16-tiles per wave, cached vector-load staging, LDP=200 padding,
// XCD-chunked blockIdx swizzle. All later structural experiments (direct-global A,
// register prefetch, global_load_lds) measured slower -- do not reintroduce.
__global__ __launch_bounds__(1024) void stageA(const short* __restrict__ Rb,
                                               const short* __restrict__ XTb,
                                               short* __restrict__ ypart) {
  __shared__ __align__(16) short ldsR[DD * LDP];
  __shared__ __align__(16) short lds2[DD * LDP];
  const int tid = threadIdx.x;
  const int bx0 = blockIdx.x;
  const int bx = (bx0 & 7) * 32 + (bx0 >> 3);   // XCD-chunked swizzle (256 = 8*32, bijective)
  const int b = bx >> 5, i = (bx >> 1) & 15, jg = bx & 1;
  const int lane15 = tid & 15, quad = (tid & 63) >> 4;
  const int wid = tid >> 6;   // 0..15
  const int wm = wid & 3;     // 4 groups x 3 tiles (B-operand dim)
  const int wq = wid >> 2;    // 4 groups x 3 tiles (A-operand dim)

  f32x4 acc_y[3][3];
  #pragma unroll
  for (int a = 0; a < 3; ++a)
    #pragma unroll
    for (int c = 0; c < 3; ++c) acc_y[a][c] = (f32x4){0.f, 0.f, 0.f, 0.f};

  for (int jj = 0; jj < 8; ++jj) {
    const int j = jg * 8 + jj;
    const short* srcR = Rb + (size_t)(i * CC + j) * (DD * DD);
    const short* srcX = XTb + (size_t)(b * CC + j) * (DD * DD);
    __syncthreads();  // previous iter done reading ldsR/lds2
    for (int c = tid; c < DD * CH; c += 1024) {
      int row = c / CH, col = c % CH;
      *(s8v*)(&ldsR[row * LDP + col * 8]) = *(const s8v*)(srcR + (size_t)c * 8);
      *(s8v*)(&lds2[row * LDP + col * 8]) = *(const s8v*)(srcX + (size_t)c * 8);
    }
    __syncthreads();

    // mm1: T^T  (A = XT rows -> wq covers 3 q-tiles; B = R rows -> wm covers 3 m-tiles)
    f32x4 acc_t[3][3];
    #pragma unroll
    for (int a = 0; a < 3; ++a)
      #pragma unroll
      for (int c = 0; c < 3; ++c) acc_t[a][c] = (f32x4){0.f, 0.f, 0.f, 0.f};

    #pragma unroll
    for (int kc = 0; kc < 6; ++kc) {
      s8v af[3], bf[3];
      #pragma unroll
      for (int a = 0; a < 3; ++a)
        af[a] = *(const s8v*)(&lds2[((wq * 3 + a) * 16 + lane15) * LDP + kc * 32 + quad * 8]);
      #pragma unroll
      for (int c = 0; c < 3; ++c)
        bf[c] = *(const s8v*)(&ldsR[((wm * 3 + c) * 16 + lane15) * LDP + kc * 32 + quad * 8]);
      #pragma unroll
      for (int a = 0; a < 3; ++a)
        #pragma unroll
        for (int c = 0; c < 3; ++c)
          acc_t[a][c] = __builtin_amdgcn_mfma_f32_16x16x32_bf16(af[a], bf[c], acc_t[a][c], 0, 0, 0);
    }
    __syncthreads();   // X fully consumed

    // pack T[m][q] (bf16) into lds2
    #pragma unroll
    for (int a = 0; a < 3; ++a) {
      #pragma unroll
      for (int c = 0; c < 3; ++c) {
        s4v pk;
        #pragma unroll
        for (int r = 0; r < 4; ++r) pk[r] = rne_bf16(acc_t[a][c][r]);
        int m = (wm * 3 + c) * 16 + lane15;
        int q0 = (wq * 3 + a) * 16 + quad * 4;
        *(s4v*)(&lds2[m * LDP + q0]) = pk;
      }
    }
    __syncthreads();

    // mm2: y[m][n] += T rows x R rows  (A = T -> wq covers 3 m-tiles; B = R -> wm covers 3 n-tiles)
    #pragma unroll
    for (int kc = 0; kc < 6; ++kc) {
      s8v af[3], bf[3];
      #pragma unroll
      for (int a = 0; a < 3; ++a)
        af[a] = *(const s8v*)(&lds2[((wq * 3 + a) * 16 + lane15) * LDP + kc * 32 + quad * 8]);
      #pragma unroll
      for (int c = 0; c < 3; ++c)
        bf[c] = *(const s8v*)(&ldsR[((wm * 3 + c) * 16 + lane15) * LDP + kc * 32 + quad * 8]);
      #pragma unroll
      for (int a = 0; a < 3; ++a)
        #pragma unroll
        for (int c = 0; c < 3; ++c)
          acc_y[a][c] = __builtin_amdgcn_mfma_f32_16x16x32_bf16(af[a], bf[c], acc_y[a][c], 0, 0, 0);
    }
  }

  // pack y^T [n][m] into lds2, then coalesced store
  __syncthreads();
  #pragma unroll
  for (int a = 0; a < 3; ++a) {
    #pragma unroll
    for (int c = 0; c < 3; ++c) {
      s4v pk;
      #pragma unroll
      for (int r = 0; r < 4; ++r) pk[r] = rne_bf16(acc_y[a][c][r]);
      int n = (wm * 3 + c) * 16 + lane15;       // B-row = n (col of y)
      int m0 = (wq * 3 + a) * 16 + quad * 4;    // A-row = m, 4 consecutive
      *(s4v*)(&lds2[n * LDP + m0]) = pk;
    }
  }
  __syncthreads();
  {
    short* dst = ypart + (size_t)(jg * (BB * CC) + b * CC + i) * (DD * DD);
    for (int c = tid; c < DD * CH; c += 1024) {
      int row = c / CH, col = c % CH;
      *(s8v*)(dst + (size_t)c * 8) = *(const s8v*)(&lds2[row * LDP + col * 8]);
    }
  }
}

// ---------------- fused stage B ----------------
// out[b,oc] = sum_j P[oc,j] @ y[b,j] @ PT[oc,j]
// y = ypart0 + ypart1 summed during staging; P staged from fp32 (cvt fused).
// Final store: atomicAdd into out (harness memsets out to 0 before launch);
// each out element receives exactly 4 adds (one per jg partial) -> reduce_out
// kernel and partials buffer eliminated.
#define PROWS 64
#define PTROWS 128
__global__ __launch_bounds__(512, 2) void fusedB(const short* __restrict__ ypart,
                                                 const float* __restrict__ Pf,
                                                 const short* __restrict__ PTTb,
                                                 float* __restrict__ out) {
  __shared__ __align__(16) short ldsYT[DD * LDP];     // 76.8 KB; rows 0..63 reused for U
  __shared__ __align__(16) short ldsP[PROWS * LDP];   // 25.6 KB
  __shared__ __align__(16) short ldsPT[PTROWS * LDP]; // 51.2 KB
  const int tid = threadIdx.x;
  const int bx0 = blockIdx.x;
  const int bx = (bx0 & 7) * 32 + (bx0 >> 3);   // XCD-chunked swizzle
  const int jg = bx & 3, nh = (bx >> 2) & 1, oc = (bx >> 3) & 3, b = bx >> 5;
  const int lane15 = tid & 15, quad = (tid & 63) >> 4;
  const int wid = tid >> 6;
  // mm_b1 wave grid: 4 (q) x 2 (m)
  const int wq1 = wid >> 1, wm1 = wid & 1;
  // mm_b2 wave grid: 2 (m) x 4 (n)
  const int wm2 = wid & 1, wn2 = wid >> 1;

  f32x4 acc_o[2][2];
  #pragma unroll
  for (int a = 0; a < 2; ++a)
    #pragma unroll
    for (int e = 0; e < 2; ++e) acc_o[a][e] = (f32x4){0.f, 0.f, 0.f, 0.f};

  const s8v z = {0, 0, 0, 0, 0, 0, 0, 0};
  for (int jj = 0; jj < 4; ++jj) {
    const int j = jg * 4 + jj;
    __syncthreads();  // prev iter done reading U/ldsP/ldsPT
    {
      const short* sy0 = ypart + (size_t)(b * CC + j) * (DD * DD);
      const short* sy1 = sy0 + (size_t)(BB * CC) * (DD * DD);
      for (int c = tid; c < DD * CH; c += 512) {
        int row = c / CH, col = c % CH;
        s8v v0 = *(const s8v*)(sy0 + (size_t)c * 8);
        s8v v1 = *(const s8v*)(sy1 + (size_t)c * 8);
        s8v o;
        #pragma unroll
        for (int r = 0; r < 8; ++r) o[r] = rne_bf16(bf2f(v0[r]) + bf2f(v1[r]));
        *(s8v*)(&ldsYT[row * LDP + col * 8]) = o;
      }
      const float* sp = Pf + (size_t)(oc * CC + j) * (OHH * DD);
      for (int c = tid; c < PROWS * CH; c += 512) {
        int row = c / CH, col = c % CH;
        s8v w = z;
        if (c < OHH * CH) {
          f4v v0 = *(const f4v*)(sp + (size_t)c * 8);
          f4v v1 = *(const f4v*)(sp + (size_t)c * 8 + 4);
          #pragma unroll
          for (int r = 0; r < 4; ++r) w[r] = rne_bf16(v0[r]);
          #pragma unroll
          for (int r = 0; r < 4; ++r) w[r + 4] = rne_bf16(v1[r]);
        }
        *(s8v*)(&ldsP[row * LDP + col * 8]) = w;
      }
      const short* st = PTTb + (size_t)(oc * CC + j) * (OWW * DD) + (size_t)nh * 100 * DD;
      for (int c = tid; c < PTROWS * CH; c += 512) {
        int row = c / CH, col = c % CH;
        *(s8v*)(&ldsPT[row * LDP + col * 8]) =
            (c < 100 * CH) ? *(const s8v*)(st + (size_t)c * 8) : z;
      }
    }
    __syncthreads();

    // mm_b1: U^T[q][m]; wq1 -> 3 q-tiles, wm1 -> 2 m-tiles
    f32x4 acc_t[3][2];
    #pragma unroll
    for (int a = 0; a < 3; ++a)
      #pragma unroll
      for (int c = 0; c < 2; ++c) acc_t[a][c] = (f32x4){0.f, 0.f, 0.f, 0.f};
    #pragma unroll
    for (int kc = 0; kc < 6; ++kc) {
      s8v af[3], bf[2];
      #pragma unroll
      for (int a = 0; a < 3; ++a)
        af[a] = *(const s8v*)(&ldsYT[((wq1 * 3 + a) * 16 + lane15) * LDP + kc * 32 + quad * 8]);
      #pragma unroll
      for (int c = 0; c < 2; ++c)
        bf[c] = *(const s8v*)(&ldsP[((wm1 * 2 + c) * 16 + lane15) * LDP + kc * 32 + quad * 8]);
      #pragma unroll
      for (int a = 0; a < 3; ++a)
        #pragma unroll
        for (int c = 0; c < 2; ++c)
          acc_t[a][c] = __builtin_amdgcn_mfma_f32_16x16x32_bf16(af[a], bf[c], acc_t[a][c], 0, 0, 0);
    }
    __syncthreads();  // yT fully consumed

    // pack U[m][q] into ldsYT rows 0..63
    #pragma unroll
    for (int a = 0; a < 3; ++a) {
      #pragma unroll
      for (int c = 0; c < 2; ++c) {
        s4v pk;
        #pragma unroll
        for (int r = 0; r < 4; ++r) pk[r] = rne_bf16(acc_t[a][c][r]);
        int m = (wm1 * 2 + c) * 16 + lane15;
        int q0 = (wq1 * 3 + a) * 16 + quad * 4;
        *(s4v*)(&ldsYT[m * LDP + q0]) = pk;
      }
    }
    __syncthreads();

    // mm_b2: out[m][n] += U rows x PT^T rows; wm2 -> 2 m-tiles, wn2 -> 2 n-tiles
    #pragma unroll
    for (int kc = 0; kc < 6; ++kc) {
      s8v af[2], bf[2];
      #pragma unroll
      for (int a = 0; a < 2; ++a)
        af[a] = *(const s8v*)(&ldsYT[((wm2 * 2 + a) * 16 + lane15) * LDP + kc * 32 + quad * 8]);
      #pragma unroll
      for (int e = 0; e < 2; ++e)
        bf[e] = *(const s8v*)(&ldsPT[((wn2 * 2 + e) * 16 + lane15) * LDP + kc * 32 + quad * 8]);
      #pragma unroll
      for (int a = 0; a < 2; ++a)
        #pragma unroll
        for (int e = 0; e < 2; ++e)
          acc_o[a][e] = __builtin_amdgcn_mfma_f32_16x16x32_bf16(af[a], bf[e], acc_o[a][e], 0, 0, 0);
    }
  }

  // atomic accumulate partial into out[b*OCC+oc][m][nh*100 + n]
  float* dst = out + (size_t)(b * OCC + oc) * (OHH * OWW);
  #pragma unroll
  for (int a = 0; a < 2; ++a) {
    #pragma unroll
    for (int e = 0; e < 2; ++e) {
      int n = (wn2 * 2 + e) * 16 + lane15;
      if (n < 100) {
        #pragma unroll
        for (int r = 0; r < 4; ++r) {
          int m = (wm2 * 2 + a) * 16 + quad * 4 + r;
          if (m < OHH)
            atomicAdd(&dst[(size_t)m * OWW + nh * 100 + n], acc_o[a][e][r]);
        }
      }
    }
  }
}

// ---------------- launcher ----------------

extern "C" void kernel_launch(void* const* d_in, const int* in_sizes, int n_in,
                              void* d_out, int out_size, void* d_ws, size_t ws_size,
                              hipStream_t stream) {
  const float* x  = (const float*)d_in[0];
  const float* R  = (const float*)d_in[1];
  const float* P  = (const float*)d_in[2];
  const float* PT = (const float*)d_in[3];
  float* out = (float*)d_out;

  short* W = (short*)d_ws;
  const size_t nR   = (size_t)CC * CC * DD * DD;     // 9,437,184
  const size_t nX   = (size_t)BB * CC * DD * DD;     // 4,718,592
  const size_t nPT  = (size_t)OCC * CC * OWW * DD;   // 2,457,600
  short* Rb    = W;
  short* XTb   = Rb + nR;
  short* PTTb  = XTb + nX;
  short* ypart = PTTb + nPT;                         // 2 halves

  prep<<<NTX + NPT + NCV, 256, 0, stream>>>(x, R, PT, XTb, PTTb, Rb);

  stageA<<<BB * CC * 2, 1024, 0, stream>>>(Rb, XTb, ypart);
  fusedB<<<BB * OCC * 2 * 4, 512, 0, stream>>>(ypart, P, PTTb, out);
}